// Round 1
// baseline (299.772 us; speedup 1.0000x reference)
//
#include <hip/hip_runtime.h>
#include <math.h>

#define NN 10000
#define EE 640000
#define DD 256

// ws layout (floats):
// [0, N)        dinv   (deg accumulated, then transformed to deg^-0.5)
// [N, 2N)       xw     (x @ W1)
// [2N, 3N)      c1
// [3N, 4N)      c2
// [4N, 5N)      c3
// [5N, 5N+144)  xp1    (48 x 3 pooled after stage 1)
// [5N+144]      regAcc (sum of row entropies of S1)

// K1: xw[i] = dot(x[i,:], W1); deg[i] = 1 (self-loop); zero xp1+regAcc.
__global__ void k_xw_init(const float* __restrict__ x, const float* __restrict__ W1,
                          float* __restrict__ xw, float* __restrict__ deg,
                          float* __restrict__ xp1reg) {
    int tid = threadIdx.x;
    int w = tid >> 6, lane = tid & 63;
    if (blockIdx.x == 0 && tid < 145) xp1reg[tid] = 0.0f;
    int node = blockIdx.x * 4 + w;
    if (node >= NN) return;
    const float4* xr = reinterpret_cast<const float4*>(x + (size_t)node * DD);
    const float4* wr = reinterpret_cast<const float4*>(W1);
    float4 a = xr[lane], b = wr[lane];
    float v = a.x * b.x + a.y * b.y + a.z * b.z + a.w * b.w;
    #pragma unroll
    for (int off = 32; off; off >>= 1) v += __shfl_xor(v, off);
    if (lane == 0) { xw[node] = v; deg[node] = 1.0f; }
}

// K2: deg[dst[e]] += ew[e]
__global__ void k_deg(const int* __restrict__ dst, const float* __restrict__ ew,
                      float* __restrict__ deg) {
    int e = blockIdx.x * blockDim.x + threadIdx.x;
    if (e < EE) atomicAdd(&deg[dst[e]], ew[e]);
}

// K3: deg -> deg^{-1/2}
__global__ void k_dinv(float* __restrict__ deg) {
    int i = blockIdx.x * blockDim.x + threadIdx.x;
    if (i < NN) {
        float d = deg[i];
        deg[i] = (d > 0.0f) ? (1.0f / sqrtf(d)) : 0.0f;
    }
}

// conv init: out[i] = dinv[i]^2 * in[i]*mult + bias   (self-loop + bias)
__global__ void k_conv_init(const float* __restrict__ in, const float* __restrict__ dinv,
                            const float* __restrict__ mult, const float* __restrict__ bias,
                            float* __restrict__ out) {
    int i = blockIdx.x * blockDim.x + threadIdx.x;
    if (i < NN) {
        float m = mult ? *mult : 1.0f;
        float di = dinv[i];
        out[i] = di * di * in[i] * m + *bias;
    }
}

// conv edges: out[dst] += dinv[src]*ew*dinv[dst] * in[src]*mult
__global__ void k_conv_edge(const int* __restrict__ src, const int* __restrict__ dst,
                            const float* __restrict__ ew, const float* __restrict__ dinv,
                            const float* __restrict__ in, const float* __restrict__ mult,
                            float* __restrict__ out) {
    int e = blockIdx.x * blockDim.x + threadIdx.x;
    if (e < EE) {
        float m = mult ? *mult : 1.0f;
        int s = src[e], d = dst[e];
        atomicAdd(&out[d], dinv[s] * ew[e] * dinv[d] * in[s] * m);
    }
}

// Pool stage 1: S1 = softmax(P1 rows, 48); xp1 += S1^T h; regAcc += row entropies.
// One wave per row; lane j owns S column j, so partial xp lives in registers.
__global__ void k_pool1(const float* __restrict__ P1, const float* __restrict__ c1,
                        const float* __restrict__ c2, const float* __restrict__ c3,
                        float* __restrict__ xp1, float* __restrict__ regAcc) {
    __shared__ float part[4][48][3];
    __shared__ float entW[4];
    int tid = threadIdx.x, w = tid >> 6, lane = tid & 63;
    float a0 = 0.f, a1 = 0.f, a2 = 0.f, ent = 0.f;
    for (int i = blockIdx.x * 4 + w; i < NN; i += gridDim.x * 4) {
        float v = (lane < 48) ? P1[i * 48 + lane] : -1e30f;
        float mx = v;
        #pragma unroll
        for (int off = 32; off; off >>= 1) mx = fmaxf(mx, __shfl_xor(mx, off));
        float e = (lane < 48) ? expf(v - mx) : 0.0f;
        float sum = e;
        #pragma unroll
        for (int off = 32; off; off >>= 1) sum += __shfl_xor(sum, off);
        float p = e / sum;
        if (lane < 48) {
            ent -= p * logf(p + 1e-12f);
            float h0 = c1[i], h1 = c2[i], h2 = c3[i];
            a0 += p * h0; a1 += p * h1; a2 += p * h2;
        }
    }
    #pragma unroll
    for (int off = 32; off; off >>= 1) ent += __shfl_xor(ent, off);
    if (lane == 0) entW[w] = ent;
    if (lane < 48) { part[w][lane][0] = a0; part[w][lane][1] = a1; part[w][lane][2] = a2; }
    __syncthreads();
    if (tid < 144) {
        int j = tid / 3, col = tid % 3;
        float s = part[0][j][col] + part[1][j][col] + part[2][j][col] + part[3][j][col];
        atomicAdd(&xp1[j * 3 + col], s);
    }
    if (tid == 0) atomicAdd(regAcc, entW[0] + entW[1] + entW[2] + entW[3]);
}

// Pool stages 2..4 (tiny) + final output. Single block.
__global__ void k_pool234(const float* __restrict__ P2, const float* __restrict__ P3,
                          const float* __restrict__ P4, const float* __restrict__ xp1,
                          const float* __restrict__ regAcc, float* __restrict__ out) {
    __shared__ float S2[48][12], xp2[12][3];
    __shared__ float S3[12][4], xp3[4][3];
    __shared__ float ent2, ent3;
    int t = threadIdx.x;
    if (t == 0) { ent2 = 0.0f; ent3 = 0.0f; }
    __syncthreads();
    if (t < 48) {
        float v[12], mx = -1e30f;
        #pragma unroll
        for (int j = 0; j < 12; j++) { v[j] = P2[t * 12 + j]; mx = fmaxf(mx, v[j]); }
        float s = 0.f;
        #pragma unroll
        for (int j = 0; j < 12; j++) { v[j] = expf(v[j] - mx); s += v[j]; }
        float e = 0.f;
        #pragma unroll
        for (int j = 0; j < 12; j++) {
            float p = v[j] / s; S2[t][j] = p; e -= p * logf(p + 1e-12f);
        }
        atomicAdd(&ent2, e);
    }
    __syncthreads();
    if (t < 36) {
        int j = t / 3, col = t % 3;
        float s = 0.f;
        for (int i = 0; i < 48; i++) s += S2[i][j] * xp1[i * 3 + col];
        xp2[j][col] = s;
    }
    __syncthreads();
    if (t < 12) {
        float v[4], mx = -1e30f;
        #pragma unroll
        for (int j = 0; j < 4; j++) { v[j] = P3[t * 4 + j]; mx = fmaxf(mx, v[j]); }
        float s = 0.f;
        #pragma unroll
        for (int j = 0; j < 4; j++) { v[j] = expf(v[j] - mx); s += v[j]; }
        float e = 0.f;
        #pragma unroll
        for (int j = 0; j < 4; j++) {
            float p = v[j] / s; S3[t][j] = p; e -= p * logf(p + 1e-12f);
        }
        atomicAdd(&ent3, e);
    }
    __syncthreads();
    if (t < 12) {
        int j = t / 3, col = t % 3;
        float s = 0.f;
        for (int i = 0; i < 12; i++) s += S3[i][j] * xp2[i][col];
        xp3[j][col] = s;
    }
    __syncthreads();
    if (t == 0) {
        // Stage 4: P4 is (4,1): softmax over 1 element == 1.0 exactly.
        float reg4 = -logf(1.0f + 1e-12f);      // per-row entropy, mean over 4 rows equals it
        float o0 = 0.f, o1 = 0.f, o2 = 0.f;
        for (int i = 0; i < 4; i++) { o0 += xp3[i][0]; o1 += xp3[i][1]; o2 += xp3[i][2]; }
        float reg = (*regAcc) / (float)NN + ent2 / 48.0f + ent3 / 12.0f + reg4;
        out[0] = o0; out[1] = o1; out[2] = o2; out[3] = reg;
    }
}

extern "C" void kernel_launch(void* const* d_in, const int* in_sizes, int n_in,
                              void* d_out, int out_size, void* d_ws, size_t ws_size,
                              hipStream_t stream) {
    const float* x  = (const float*)d_in[0];
    const int*   ei = (const int*)d_in[1];
    const float* ea = (const float*)d_in[2];
    // d_in[3] = adj — unused by the reference.
    const float* W1 = (const float*)d_in[4];
    const float* b1 = (const float*)d_in[5];
    const float* W2 = (const float*)d_in[6];
    const float* b2 = (const float*)d_in[7];
    const float* P1 = (const float*)d_in[8];
    const float* P2 = (const float*)d_in[9];
    const float* P3 = (const float*)d_in[10];
    const float* P4 = (const float*)d_in[11];
    const int* src = ei;
    const int* dst = ei + EE;

    float* ws     = (float*)d_ws;
    float* dinv   = ws;
    float* xw     = ws + NN;
    float* c1     = ws + 2 * NN;
    float* c2     = ws + 3 * NN;
    float* c3     = ws + 4 * NN;
    float* xp1    = ws + 5 * NN;          // 144 floats
    float* regAcc = ws + 5 * NN + 144;    // 1 float
    float* out    = (float*)d_out;

    const int EB = (EE + 255) / 256;
    const int NB = (NN + 255) / 256;

    k_xw_init<<<2500, 256, 0, stream>>>(x, W1, xw, dinv, xp1);
    k_deg<<<EB, 256, 0, stream>>>(dst, ea, dinv);
    k_dinv<<<NB, 256, 0, stream>>>(dinv);

    k_conv_init<<<NB, 256, 0, stream>>>(xw, dinv, nullptr, b1, c1);
    k_conv_edge<<<EB, 256, 0, stream>>>(src, dst, ea, dinv, xw, nullptr, c1);
    k_conv_init<<<NB, 256, 0, stream>>>(c1, dinv, W2, b2, c2);
    k_conv_edge<<<EB, 256, 0, stream>>>(src, dst, ea, dinv, c1, W2, c2);
    k_conv_init<<<NB, 256, 0, stream>>>(c2, dinv, W2, b2, c3);
    k_conv_edge<<<EB, 256, 0, stream>>>(src, dst, ea, dinv, c2, W2, c3);

    k_pool1<<<40, 256, 0, stream>>>(P1, c1, c2, c3, xp1, regAcc);
    k_pool234<<<1, 64, 0, stream>>>(P2, P3, P4, xp1, regAcc, out);
}

// Round 2
// 140.782 us; speedup vs baseline: 2.1293x; 2.1293x over previous
//
#include <hip/hip_runtime.h>
#include <math.h>

#define NN 10000
#define EE 640000
#define DD 256
#define BPASS 128   // blocks per edge pass; EE/BPASS = 5000 edges/block exactly

// ws layout (floats):
// [0, N)            dinv
// [N, 2N)           xw     (x @ W1)
// [2N, 3N)          c1
// [3N, 4N)          c2
// [4N, 5N)          c3
// [5N, 5N+144)      xp1    (48 x 3 pooled after stage 1)
// [5N+144]          regAcc
// [5N+160, +BPASS*N) partials

// K1: xw[i] = dot(x[i,:], W1); zero xp1+regAcc.
__global__ void k_xw_init(const float* __restrict__ x, const float* __restrict__ W1,
                          float* __restrict__ xw, float* __restrict__ xp1reg) {
    int tid = threadIdx.x;
    int w = tid >> 6, lane = tid & 63;
    if (blockIdx.x == 0 && tid < 145) xp1reg[tid] = 0.0f;
    int node = blockIdx.x * 4 + w;
    if (node >= NN) return;
    const float4* xr = reinterpret_cast<const float4*>(x + (size_t)node * DD);
    const float4* wr = reinterpret_cast<const float4*>(W1);
    float4 a = xr[lane], b = wr[lane];
    float v = a.x * b.x + a.y * b.y + a.z * b.z + a.w * b.w;
    #pragma unroll
    for (int off = 32; off; off >>= 1) v += __shfl_xor(v, off);
    if (lane == 0) xw[node] = v;
}

// Edge pass: per-block LDS accumulator over the full node range, then write
// partials[blockIdx][*]. USE_SRC=false: accumulate ew (degree). USE_SRC=true:
// accumulate dinv[src]*ew*in[src]  (dinv[dst], mult, bias folded into reduce).
template <bool USE_SRC>
__global__ __launch_bounds__(256) void k_edge_acc(const int* __restrict__ src,
                                                  const int* __restrict__ dst,
                                                  const float* __restrict__ ew,
                                                  const float* __restrict__ dinv,
                                                  const float* __restrict__ in,
                                                  float* __restrict__ partials) {
    __shared__ float acc[NN];
    for (int i = threadIdx.x; i < NN; i += 256) acc[i] = 0.0f;
    __syncthreads();
    const int per = EE / BPASS;            // 5000
    const int base = blockIdx.x * per;
    for (int k = threadIdx.x; k < per; k += 256) {
        int e = base + k;
        int d = dst[e];
        float v = ew[e];
        if (USE_SRC) {
            int s = src[e];
            v *= dinv[s] * in[s];
        }
        atomicAdd(&acc[d], v);             // LDS atomic (ds_add_f32)
    }
    __syncthreads();
    float* p = partials + (size_t)blockIdx.x * NN;
    for (int i = threadIdx.x; i < NN; i += 256) p[i] = acc[i];
}

// dinv[i] = (1 + sum_b partials[b][i])^{-1/2}
__global__ void k_reduce_dinv(const float* __restrict__ partials, float* __restrict__ dinv) {
    int i = blockIdx.x * 256 + threadIdx.x;
    if (i >= NN) return;
    float s = 1.0f;                        // self-loop weight
    for (int b = 0; b < BPASS; b++) s += partials[(size_t)b * NN + i];
    dinv[i] = (s > 0.0f) ? (1.0f / sqrtf(s)) : 0.0f;
}

// out[i] = mult * dinv[i] * (sum_b partials[b][i] + dinv[i]*in[i]) + bias
__global__ void k_reduce_conv(const float* __restrict__ partials, const float* __restrict__ dinv,
                              const float* __restrict__ in, const float* __restrict__ mult,
                              const float* __restrict__ bias, float* __restrict__ out) {
    int i = blockIdx.x * 256 + threadIdx.x;
    if (i >= NN) return;
    float di = dinv[i];
    float acc = di * in[i];                // self-loop term (before outer dinv[d])
    for (int b = 0; b < BPASS; b++) acc += partials[(size_t)b * NN + i];
    float m = mult ? *mult : 1.0f;
    out[i] = m * di * acc + *bias;
}

// Pool stage 1: S1 = softmax(P1 rows, 48); xp1 += S1^T h; regAcc += row entropies.
__global__ void k_pool1(const float* __restrict__ P1, const float* __restrict__ c1,
                        const float* __restrict__ c2, const float* __restrict__ c3,
                        float* __restrict__ xp1, float* __restrict__ regAcc) {
    __shared__ float part[4][48][3];
    __shared__ float entW[4];
    int tid = threadIdx.x, w = tid >> 6, lane = tid & 63;
    float a0 = 0.f, a1 = 0.f, a2 = 0.f, ent = 0.f;
    for (int i = blockIdx.x * 4 + w; i < NN; i += gridDim.x * 4) {
        float v = (lane < 48) ? P1[i * 48 + lane] : -1e30f;
        float mx = v;
        #pragma unroll
        for (int off = 32; off; off >>= 1) mx = fmaxf(mx, __shfl_xor(mx, off));
        float e = (lane < 48) ? expf(v - mx) : 0.0f;
        float sum = e;
        #pragma unroll
        for (int off = 32; off; off >>= 1) sum += __shfl_xor(sum, off);
        float p = e / sum;
        if (lane < 48) {
            ent -= p * logf(p + 1e-12f);
            a0 += p * c1[i]; a1 += p * c2[i]; a2 += p * c3[i];
        }
    }
    #pragma unroll
    for (int off = 32; off; off >>= 1) ent += __shfl_xor(ent, off);
    if (lane == 0) entW[w] = ent;
    if (lane < 48) { part[w][lane][0] = a0; part[w][lane][1] = a1; part[w][lane][2] = a2; }
    __syncthreads();
    if (tid < 144) {
        int j = tid / 3, col = tid % 3;
        float s = part[0][j][col] + part[1][j][col] + part[2][j][col] + part[3][j][col];
        atomicAdd(&xp1[j * 3 + col], s);
    }
    if (tid == 0) atomicAdd(regAcc, entW[0] + entW[1] + entW[2] + entW[3]);
}

// Pool stages 2..4 (tiny) + final output. Single block.
__global__ void k_pool234(const float* __restrict__ P2, const float* __restrict__ P3,
                          const float* __restrict__ P4, const float* __restrict__ xp1,
                          const float* __restrict__ regAcc, float* __restrict__ out) {
    __shared__ float S2[48][12], xp2[12][3];
    __shared__ float S3[12][4], xp3[4][3];
    __shared__ float ent2, ent3;
    int t = threadIdx.x;
    if (t == 0) { ent2 = 0.0f; ent3 = 0.0f; }
    __syncthreads();
    if (t < 48) {
        float v[12], mx = -1e30f;
        #pragma unroll
        for (int j = 0; j < 12; j++) { v[j] = P2[t * 12 + j]; mx = fmaxf(mx, v[j]); }
        float s = 0.f;
        #pragma unroll
        for (int j = 0; j < 12; j++) { v[j] = expf(v[j] - mx); s += v[j]; }
        float e = 0.f;
        #pragma unroll
        for (int j = 0; j < 12; j++) {
            float p = v[j] / s; S2[t][j] = p; e -= p * logf(p + 1e-12f);
        }
        atomicAdd(&ent2, e);
    }
    __syncthreads();
    if (t < 36) {
        int j = t / 3, col = t % 3;
        float s = 0.f;
        for (int i = 0; i < 48; i++) s += S2[i][j] * xp1[i * 3 + col];
        xp2[j][col] = s;
    }
    __syncthreads();
    if (t < 12) {
        float v[4], mx = -1e30f;
        #pragma unroll
        for (int j = 0; j < 4; j++) { v[j] = P3[t * 4 + j]; mx = fmaxf(mx, v[j]); }
        float s = 0.f;
        #pragma unroll
        for (int j = 0; j < 4; j++) { v[j] = expf(v[j] - mx); s += v[j]; }
        float e = 0.f;
        #pragma unroll
        for (int j = 0; j < 4; j++) {
            float p = v[j] / s; S3[t][j] = p; e -= p * logf(p + 1e-12f);
        }
        atomicAdd(&ent3, e);
    }
    __syncthreads();
    if (t < 12) {
        int j = t / 3, col = t % 3;
        float s = 0.f;
        for (int i = 0; i < 12; i++) s += S3[i][j] * xp2[i][col];
        xp3[j][col] = s;
    }
    __syncthreads();
    if (t == 0) {
        float reg4 = -logf(1.0f + 1e-12f);   // softmax over width-1 rows: p==1
        float o0 = 0.f, o1 = 0.f, o2 = 0.f;
        for (int i = 0; i < 4; i++) { o0 += xp3[i][0]; o1 += xp3[i][1]; o2 += xp3[i][2]; }
        float reg = (*regAcc) / (float)NN + ent2 / 48.0f + ent3 / 12.0f + reg4;
        out[0] = o0; out[1] = o1; out[2] = o2; out[3] = reg;
    }
}

extern "C" void kernel_launch(void* const* d_in, const int* in_sizes, int n_in,
                              void* d_out, int out_size, void* d_ws, size_t ws_size,
                              hipStream_t stream) {
    const float* x  = (const float*)d_in[0];
    const int*   ei = (const int*)d_in[1];
    const float* ea = (const float*)d_in[2];
    // d_in[3] = adj — unused by the reference.
    const float* W1 = (const float*)d_in[4];
    const float* b1 = (const float*)d_in[5];
    const float* W2 = (const float*)d_in[6];
    const float* b2 = (const float*)d_in[7];
    const float* P1 = (const float*)d_in[8];
    const float* P2 = (const float*)d_in[9];
    const float* P3 = (const float*)d_in[10];
    const float* P4 = (const float*)d_in[11];
    const int* src = ei;
    const int* dst = ei + EE;

    float* ws       = (float*)d_ws;
    float* dinv     = ws;
    float* xw       = ws + NN;
    float* c1       = ws + 2 * NN;
    float* c2       = ws + 3 * NN;
    float* c3       = ws + 4 * NN;
    float* xp1      = ws + 5 * NN;          // 144 floats
    float* regAcc   = ws + 5 * NN + 144;    // 1 float
    float* partials = ws + 5 * NN + 160;    // BPASS * NN floats
    float* out      = (float*)d_out;

    const int NB = (NN + 255) / 256;        // 40

    k_xw_init<<<2500, 256, 0, stream>>>(x, W1, xw, xp1);

    k_edge_acc<false><<<BPASS, 256, 0, stream>>>(src, dst, ea, nullptr, nullptr, partials);
    k_reduce_dinv<<<NB, 256, 0, stream>>>(partials, dinv);

    k_edge_acc<true><<<BPASS, 256, 0, stream>>>(src, dst, ea, dinv, xw, partials);
    k_reduce_conv<<<NB, 256, 0, stream>>>(partials, dinv, xw, nullptr, b1, c1);

    k_edge_acc<true><<<BPASS, 256, 0, stream>>>(src, dst, ea, dinv, c1, partials);
    k_reduce_conv<<<NB, 256, 0, stream>>>(partials, dinv, c1, W2, b2, c2);

    k_edge_acc<true><<<BPASS, 256, 0, stream>>>(src, dst, ea, dinv, c2, partials);
    k_reduce_conv<<<NB, 256, 0, stream>>>(partials, dinv, c2, W2, b2, c3);

    k_pool1<<<40, 256, 0, stream>>>(P1, c1, c2, c3, xp1, regAcc);
    k_pool234<<<1, 64, 0, stream>>>(P2, P3, P4, xp1, regAcc, out);
}